// Round 6
// baseline (211.052 us; speedup 1.0000x reference)
//
#include <hip/hip_runtime.h>
#include <hip/hip_bf16.h>
#include <cstdint>

// MultiHeadSelfAttention N=2,L=2048,E=1024,H=16,D=64.
// Round 6: attn with 64q/wave (4x LDS reuse vs r4), 2-wave blocks (grid 512,
// 2 independent blocks/CU), double-buffered XOR-swizzled K/V LDS + register
// prefetch, 1 barrier/kt. No-max exp2 softmax, mask as C-init bias, l via
// ones-MFMA, wave-private stride-72 P tile (all r3/r4-verified).
// conv kernel folded into proj (z==3 slice does Wo+bias; proj reads W f32).

#define NB 2
#define LSEQ 2048
#define EMB 1024
#define NHEADS 16
#define HD 64

// (1/sqrt(1024)) * log2(e): folded into Wq conversion; P = exp2(S + bias)
#define QSCALE 0.045084220027780106f
#define MASKBIAS -1e30f

using short8 = __attribute__((ext_vector_type(8))) short;
using short4v = __attribute__((ext_vector_type(4))) short;
using f32x4 = __attribute__((ext_vector_type(4))) float;

__device__ inline short bf16of(float f) {
  union { __hip_bfloat16 b; short s; } u;
  u.b = __float2bfloat16(f);
  return u.s;
}

__device__ inline short4v pack4bf(float a, float b, float c, float d) {
  union { __hip_bfloat162 v[2]; short4v s; } u;
  u.v[0] = __float22bfloat162_rn(make_float2(a, b));
  u.v[1] = __float22bfloat162_rn(make_float2(c, d));
  return u.s;
}

__device__ inline short8 pack8bf(float4 a, float4 b) {
  union { short4v q[2]; short8 o; } u;
  u.q[0] = pack4bf(a.x, a.y, a.z, a.w);
  u.q[1] = pack4bf(b.x, b.y, b.z, b.w);
  return u.o;
}

__device__ inline float fexp2(float x) {
#if __has_builtin(__builtin_amdgcn_exp2f)
  return __builtin_amdgcn_exp2f(x);
#else
  return exp2f(x);
#endif
}

#define MFMA(A, B, C) __builtin_amdgcn_mfma_f32_16x16x32_bf16((A), (B), (C), 0, 0, 0)

// ---------------------------------------------------------------------------
// Projections (z=0 Q, z=1 K, z=2 V) + conversion slice (z=3: Wo->bf16,
// mask->bias). W read as f32 (16 KB, L2-broadcast) and packed in-reg.
// z<3: block = (ltile 64, nh); LDS-staged x tile, swizzled.
__global__ __launch_bounds__(256) void proj_mfma(
    const float* __restrict__ xq, const float* __restrict__ xk,
    const float* __restrict__ xv, const float* __restrict__ Wq,
    const float* __restrict__ Wk, const float* __restrict__ Wv,
    const float* __restrict__ Wo, const int* __restrict__ mask,
    short* __restrict__ Qb, short* __restrict__ Kb, short* __restrict__ Vt,
    short* __restrict__ Wob, float* __restrict__ biasf) {
  const int z = blockIdx.z;
  const int t = threadIdx.x;
  if (z == 3) {
    const int b = blockIdx.y * 32 + blockIdx.x;  // [0,1024)
    int i = (b * 256 + t) * 4;
    float4 v = *(const float4*)&Wo[i];
    *(short4v*)&Wob[i] = pack4bf(v.x, v.y, v.z, v.w);
    if (b < 4) {
      int j = (b * 256 + t) * 4;
      int4 m = *(const int4*)&mask[j];
      float4 o;
      o.x = m.x ? 0.f : MASKBIAS;
      o.y = m.y ? 0.f : MASKBIAS;
      o.z = m.z ? 0.f : MASKBIAS;
      o.w = m.w ? 0.f : MASKBIAS;
      *(float4*)&biasf[j] = o;
    }
    return;
  }

  __shared__ __align__(16) short xs[64 * 64];
  const int wv = t >> 6, lane = t & 63;
  const int quad = lane >> 4, l15 = lane & 15;
  const int nh = blockIdx.y;
  const int n = nh >> 4, h = nh & 15;
  const int l0 = blockIdx.x * 64;
  const float* x = (z == 0) ? xq : (z == 1) ? xk : xv;
  const float* W = (z == 0) ? Wq : (z == 1) ? Wk : Wv;
  const float sc = (z == 0) ? QSCALE : 1.0f;

  // Stage x tile: 512 16B-chunks; thread handles chunks t, t+256 (coalesced
  // 8 rows x 256 B per instruction), XOR-swizzled.
#pragma unroll
  for (int i = 0; i < 2; ++i) {
    int cc = i * 256 + t, row = cc >> 3, ch = cc & 7;
    const float* g = x + ((size_t)n * LSEQ + l0 + row) * EMB + h * HD + ch * 8;
    float4 a = *(const float4*)g;
    float4 b = *(const float4*)(g + 4);
    *(short8*)&xs[row * 64 + ((ch ^ (row & 7)) * 8)] = pack8bf(a, b);
  }
  __syncthreads();

  f32x4 acc[4];
#pragma unroll
  for (int a = 0; a < 4; ++a) acc[a] = (f32x4){0.f, 0.f, 0.f, 0.f};

  if (z < 2) {
    short8 xf[2];
#pragma unroll
    for (int c = 0; c < 2; ++c)
      xf[c] = *(const short8*)&xs[(wv * 16 + l15) * 64 +
                                  (((c * 4 + quad) ^ (l15 & 7)) * 8)];
#pragma unroll
    for (int c = 0; c < 2; ++c)
#pragma unroll
      for (int mt = 0; mt < 4; ++mt) {
        const float* wr = W + (mt * 16 + l15) * HD + c * 32 + quad * 8;
        float4 wa = *(const float4*)wr;
        float4 wb = *(const float4*)(wr + 4);
        wa.x *= sc; wa.y *= sc; wa.z *= sc; wa.w *= sc;
        wb.x *= sc; wb.y *= sc; wb.z *= sc; wb.w *= sc;
        short8 wf = pack8bf(wa, wb);
        acc[mt] = MFMA(wf, xf[c], acc[mt]);
      }
    short* ob =
        ((z == 0) ? Qb : Kb) + ((size_t)nh * LSEQ + l0 + wv * 16 + l15) * HD;
#pragma unroll
    for (int mt = 0; mt < 4; ++mt)
      *(short4v*)&ob[mt * 16 + quad * 4] =
          pack4bf(acc[mt][0], acc[mt][1], acc[mt][2], acc[mt][3]);
  } else {
    short8 wf[2];
#pragma unroll
    for (int c = 0; c < 2; ++c) {
      const float* wr = W + (wv * 16 + l15) * HD + c * 32 + quad * 8;
      wf[c] = pack8bf(*(const float4*)wr, *(const float4*)(wr + 4));
    }
#pragma unroll
    for (int c = 0; c < 2; ++c)
#pragma unroll
      for (int mt = 0; mt < 4; ++mt) {
        short8 af = *(const short8*)&xs[(mt * 16 + l15) * 64 +
                                        (((c * 4 + quad) ^ (l15 & 7)) * 8)];
        acc[mt] = MFMA(af, wf[c], acc[mt]);
      }
    short* vb = Vt + ((size_t)nh * HD + wv * 16 + l15) * LSEQ + l0;
#pragma unroll
    for (int mt = 0; mt < 4; ++mt)
      *(short4v*)&vb[mt * 16 + quad * 4] =
          pack4bf(acc[mt][0], acc[mt][1], acc[mt][2], acc[mt][3]);
  }
}

// ---------------------------------------------------------------------------
// Flash attention. Wave = 64 q; block = 2 waves = 128 q. Grid (16,32) = 512
// blocks -> 2 independent blocks/CU. Double-buffered XOR-swizzled K/V LDS,
// register prefetch, 1 barrier/kt. No-max exp2 softmax; l via ones-MFMA.
__global__ __launch_bounds__(128) void attn_kernel(
    const short* __restrict__ Qg,    // [nh][L][64] bf16 (Wq pre-scaled)
    const short* __restrict__ Kg,    // [nh][L][64] bf16
    const short* __restrict__ Vtg,   // [nh][64][L] bf16
    const float* __restrict__ biasf, // [N][L]: 0 or -1e30
    short* __restrict__ AO)          // [N*L][E] bf16
{
  __shared__ __align__(16) short Ks[2][64 * 64];  // [k][d] swizzled
  __shared__ __align__(16) short Vs[2][64 * 64];  // [d][k] swizzled
  __shared__ __align__(16) short Pl[2][64 * 72];  // per-wave P[q][k]

  const int t = threadIdx.x;
  const int wv = t >> 6, lane = t & 63;
  const int quad = lane >> 4, l15 = lane & 15;
  const int nh = blockIdx.y;
  const int n = nh >> 4, h = nh & 15;
  const int q0 = blockIdx.x * 128 + wv * 64;

  const short* kbase = Kg + (size_t)nh * LSEQ * HD;
  const short* vbase = Vtg + (size_t)nh * HD * LSEQ;
  const float* bbase = biasf + n * LSEQ;

  // Resident Q B-fragments: B[d = c*32+quad*8+j][q = ntq*16+l15]
  short8 qf[4][2];
#pragma unroll
  for (int ntq = 0; ntq < 4; ++ntq)
#pragma unroll
    for (int c = 0; c < 2; ++c)
      qf[ntq][c] = *(const short8*)(Qg +
          ((size_t)nh * LSEQ + q0 + ntq * 16 + l15) * HD + c * 32 + quad * 8);

  // Staging: 512 chunks per tile over 128 threads -> 4 chunks each.
  // Chunk cc: row = cc>>3 (thread covers rows r0s+16i), ch = t&7.
  const int r0s = t >> 3, ch = t & 7;
  short8 kpre[4], vpre[4];
#pragma unroll
  for (int i = 0; i < 4; ++i) {
    int row = r0s + 16 * i;
    kpre[i] = *(const short8*)(kbase + (size_t)row * HD + ch * 8);
    vpre[i] = *(const short8*)(vbase + (size_t)row * LSEQ + ch * 8);
  }
#pragma unroll
  for (int i = 0; i < 4; ++i) {
    int row = r0s + 16 * i;
    int off = row * 64 + ((ch ^ (row & 7)) * 8);
    *(short8*)&Ks[0][off] = kpre[i];
    *(short8*)&Vs[0][off] = vpre[i];
  }
  __syncthreads();

  f32x4 O[4][4], Ol[4];
#pragma unroll
  for (int a = 0; a < 4; ++a) {
    Ol[a] = (f32x4){0.f, 0.f, 0.f, 0.f};
#pragma unroll
    for (int b = 0; b < 4; ++b) O[a][b] = (f32x4){0.f, 0.f, 0.f, 0.f};
  }
  const short one_bf = (short)0x3F80;
  const short8 ones = {one_bf, one_bf, one_bf, one_bf,
                       one_bf, one_bf, one_bf, one_bf};

  const int sw0 = ((0 * 4 + quad) ^ (l15 & 7)) * 8;
  const int sw1 = ((1 * 4 + quad) ^ (l15 & 7)) * 8;

  for (int kt = 0; kt < LSEQ / 64; ++kt) {
    const int cur = kt & 1, nxt = cur ^ 1;
    const int k0 = kt * 64;
    if (kt < LSEQ / 64 - 1) {
#pragma unroll
      for (int i = 0; i < 4; ++i) {
        int row = r0s + 16 * i;
        kpre[i] = *(const short8*)(kbase + (size_t)(k0 + 64 + row) * HD + ch * 8);
        vpre[i] = *(const short8*)(vbase + (size_t)row * LSEQ + k0 + 64 + ch * 8);
      }
    }

    // ---- S^T = K·Q^T with mask-bias C-init: St[mt(k)][ntq(q)]
    f32x4 St[4][4];
#pragma unroll
    for (int mt = 0; mt < 4; ++mt) {
      f32x4 bv = *(const f32x4*)(bbase + k0 + mt * 16 + quad * 4);
#pragma unroll
      for (int ntq = 0; ntq < 4; ++ntq) St[mt][ntq] = bv;
    }
#pragma unroll
    for (int c = 0; c < 2; ++c) {
      const int sw = c ? sw1 : sw0;
      short8 kf[4];
#pragma unroll
      for (int mt = 0; mt < 4; ++mt)
        kf[mt] = *(const short8*)&Ks[cur][(mt * 16 + l15) * 64 + sw];
#pragma unroll
      for (int mt = 0; mt < 4; ++mt)
#pragma unroll
        for (int ntq = 0; ntq < 4; ++ntq)
          St[mt][ntq] = MFMA(kf[mt], qf[ntq][c], St[mt][ntq]);
    }

    // ---- P = exp2(St); pack bf16 -> wave-private Pl[q][k]
#pragma unroll
    for (int ntq = 0; ntq < 4; ++ntq)
#pragma unroll
      for (int mt = 0; mt < 4; ++mt) {
#pragma unroll
        for (int r = 0; r < 4; ++r) St[mt][ntq][r] = fexp2(St[mt][ntq][r]);
        *(short4v*)&Pl[wv][(ntq * 16 + l15) * 72 + mt * 16 + quad * 4] =
            pack4bf(St[mt][ntq][0], St[mt][ntq][1], St[mt][ntq][2],
                    St[mt][ntq][3]);
      }

    // ---- PV + l
#pragma unroll
    for (int c = 0; c < 2; ++c) {
      const int sw = c ? sw1 : sw0;
      short8 pf[4];
#pragma unroll
      for (int mq = 0; mq < 4; ++mq)
        pf[mq] =
            *(const short8*)&Pl[wv][(mq * 16 + l15) * 72 + c * 32 + quad * 8];
#pragma unroll
      for (int ntv = 0; ntv < 4; ++ntv) {
        short8 vf = *(const short8*)&Vs[cur][(ntv * 16 + l15) * 64 + sw];
#pragma unroll
        for (int mq = 0; mq < 4; ++mq) O[mq][ntv] = MFMA(pf[mq], vf, O[mq][ntv]);
      }
#pragma unroll
      for (int mq = 0; mq < 4; ++mq) Ol[mq] = MFMA(pf[mq], ones, Ol[mq]);
    }

    if (kt < LSEQ / 64 - 1) {
#pragma unroll
      for (int i = 0; i < 4; ++i) {
        int row = r0s + 16 * i;
        int off = row * 64 + ((ch ^ (row & 7)) * 8);
        *(short8*)&Ks[nxt][off] = kpre[i];
        *(short8*)&Vs[nxt][off] = vpre[i];
      }
    }
    __syncthreads();
  }

  // ---- epilogue: O/l -> bf16 AO[n*L + q][h*64 + dv]
  short* ob = AO + ((size_t)n * LSEQ + q0) * EMB + h * HD;
#pragma unroll
  for (int mq = 0; mq < 4; ++mq) {
    f32x4 inv;
#pragma unroll
    for (int r = 0; r < 4; ++r) inv[r] = 1.f / Ol[mq][r];
#pragma unroll
    for (int ntv = 0; ntv < 4; ++ntv)
#pragma unroll
      for (int r = 0; r < 4; ++r)
        ob[(size_t)(mq * 16 + quad * 4 + r) * EMB + ntv * 16 + l15] =
            bf16of(O[mq][ntv][r] * inv[r]);
  }
}

// ---------------------------------------------------------------------------
// Out-projection: C[r][j] = sum_e A[r][e]*Wo[j][e] + bo[j].
// 128x64 tile/block, grid (16,32)=512 -> 2 blocks/CU. XOR-swizzled LDS,
// double-buffered, register prefetch. (round-4/5 verified)
__global__ __launch_bounds__(256, 2) void outproj_mfma(
    const short* __restrict__ A, const short* __restrict__ W,
    const float* __restrict__ bo, float* __restrict__ C) {
  __shared__ __align__(16) short As[2][128 * 64];
  __shared__ __align__(16) short Bs[2][64 * 64];
  const int t = threadIdx.x;
  const int wq = t >> 6, lane = t & 63;
  const int quad = lane >> 4, l15 = lane & 15;
  const int j0 = blockIdx.x * 64, r0 = blockIdx.y * 128;

  f32x4 acc[2][4];
#pragma unroll
  for (int a = 0; a < 2; ++a)
#pragma unroll
    for (int b = 0; b < 4; ++b) acc[a][b] = (f32x4){0.f, 0.f, 0.f, 0.f};

  short8 ar[4], br[2];
#pragma unroll
  for (int i = 0; i < 4; ++i) {
    int slot = i * 256 + t, row = slot >> 3, ch = slot & 7;
    ar[i] = *(const short8*)(A + (size_t)(r0 + row) * EMB + ch * 8);
  }
#pragma unroll
  for (int i = 0; i < 2; ++i) {
    int slot = i * 256 + t, row = slot >> 3, ch = slot & 7;
    br[i] = *(const short8*)(W + (size_t)(j0 + row) * EMB + ch * 8);
  }
#pragma unroll
  for (int i = 0; i < 4; ++i) {
    int slot = i * 256 + t, row = slot >> 3, ch = slot & 7;
    *(short8*)&As[0][row * 64 + ((ch ^ (row & 7)) * 8)] = ar[i];
  }
#pragma unroll
  for (int i = 0; i < 2; ++i) {
    int slot = i * 256 + t, row = slot >> 3, ch = slot & 7;
    *(short8*)&Bs[0][row * 64 + ((ch ^ (row & 7)) * 8)] = br[i];
  }
  __syncthreads();

  const int sw0 = ((0 * 4 + quad) ^ (l15 & 7)) * 8;
  const int sw1 = ((1 * 4 + quad) ^ (l15 & 7)) * 8;

  for (int ek = 0; ek < EMB; ek += 64) {
    const int cur = (ek >> 6) & 1, nxt = cur ^ 1;
    if (ek + 64 < EMB) {
#pragma unroll
      for (int i = 0; i < 4; ++i) {
        int slot = i * 256 + t, row = slot >> 3, ch = slot & 7;
        ar[i] = *(const short8*)(A + (size_t)(r0 + row) * EMB + ek + 64 + ch * 8);
      }
#pragma unroll
      for (int i = 0; i < 2; ++i) {
        int slot = i * 256 + t, row = slot >> 3, ch = slot & 7;
        br[i] = *(const short8*)(W + (size_t)(j0 + row) * EMB + ek + 64 + ch * 8);
      }
    }
#pragma unroll
    for (int c = 0; c < 2; ++c) {
      const int sw = c ? sw1 : sw0;
      short8 af[2], bf[4];
#pragma unroll
      for (int mt = 0; mt < 2; ++mt)
        af[mt] = *(const short8*)&As[cur][(wq * 32 + mt * 16 + l15) * 64 + sw];
#pragma unroll
      for (int nt = 0; nt < 4; ++nt)
        bf[nt] = *(const short8*)&Bs[cur][(nt * 16 + l15) * 64 + sw];
#pragma unroll
      for (int mt = 0; mt < 2; ++mt)
#pragma unroll
        for (int nt = 0; nt < 4; ++nt)
          acc[mt][nt] = MFMA(af[mt], bf[nt], acc[mt][nt]);
    }
    if (ek + 64 < EMB) {
#pragma unroll
      for (int i = 0; i < 4; ++i) {
        int slot = i * 256 + t, row = slot >> 3, ch = slot & 7;
        *(short8*)&As[nxt][row * 64 + ((ch ^ (row & 7)) * 8)] = ar[i];
      }
#pragma unroll
      for (int i = 0; i < 2; ++i) {
        int slot = i * 256 + t, row = slot >> 3, ch = slot & 7;
        *(short8*)&Bs[nxt][row * 64 + ((ch ^ (row & 7)) * 8)] = br[i];
      }
    }
    __syncthreads();
  }

  float bn[4];
#pragma unroll
  for (int nt = 0; nt < 4; ++nt) bn[nt] = bo[j0 + nt * 16 + l15];
#pragma unroll
  for (int mt = 0; mt < 2; ++mt)
#pragma unroll
    for (int nt = 0; nt < 4; ++nt)
#pragma unroll
      for (int r = 0; r < 4; ++r)
        C[(size_t)(r0 + wq * 32 + mt * 16 + quad * 4 + r) * EMB + j0 +
          nt * 16 + l15] = acc[mt][nt][r] + bn[nt];
}

// ---------------------------------------------------------------------------
extern "C" void kernel_launch(void* const* d_in, const int* in_sizes, int n_in,
                              void* d_out, int out_size, void* d_ws,
                              size_t ws_size, hipStream_t stream) {
  const float* values = (const float*)d_in[0];
  const float* keys   = (const float*)d_in[1];
  const float* query  = (const float*)d_in[2];
  const int*   mask   = (const int*)d_in[3];
  const float* Wv     = (const float*)d_in[4];
  const float* Wk     = (const float*)d_in[5];
  const float* Wq     = (const float*)d_in[6];
  const float* Wo     = (const float*)d_in[7];
  const float* bo     = (const float*)d_in[8];
  float* out = (float*)d_out;

  short* ws = (short*)d_ws;
  const size_t tsz = (size_t)NB * NHEADS * LSEQ * HD;  // 4 Mi shorts
  short* Qb  = ws;
  short* Kb  = Qb + tsz;
  short* Vt  = Kb + tsz;
  short* AOb = Vt + tsz;
  short* Wob = AOb + tsz;                            // 1 Mi shorts
  float* biasf = (float*)(Wob + (size_t)EMB * EMB);  // 4096 floats

  proj_mfma<<<dim3(LSEQ / 64, NB * NHEADS, 4), dim3(256), 0, stream>>>(
      query, keys, values, Wq, Wk, Wv, Wo, mask, Qb, Kb, Vt, Wob, biasf);
  attn_kernel<<<dim3(LSEQ / 128, NB * NHEADS), dim3(128), 0, stream>>>(
      Qb, Kb, Vt, biasf, AOb);
  outproj_mfma<<<dim3(EMB / 64, NB * LSEQ / 128), dim3(256), 0, stream>>>(
      AOb, Wob, bo, out);
}

// Round 7
// 189.592 us; speedup vs baseline: 1.1132x; 1.1132x over previous
//
#include <hip/hip_runtime.h>
#include <hip/hip_bf16.h>
#include <cstdint>

// MultiHeadSelfAttention N=2,L=2048,E=1024,H=16,D=64.
// Round 7: attn barrier-free — each wave owns a private 16KB K/V LDS slice
// (no __syncthreads in the k-loop), and the P LDS round-trip is ELIMINATED
// via a k-permutation pi: V is staged in pi-order so the S^T C-layout values,
// packed in-register, ARE the PV A-fragments. Per-wave-kt LDS traffic drops
// 48->32 KB and all phase-locking disappears.
// pi: k = mt*16+quad*4+r  <->  p = (mt&1)*32 + quad*8 + (mt>>1)*4 + r
//   A-frag(q,c) = [St[c][q].xyzw, St[c+2][q].xyzw]  (pure pack)
//   V^T global short8 (8 contig k) -> two b64 LDS writes at p1, p1+8.

#define NB 2
#define LSEQ 2048
#define EMB 1024
#define NHEADS 16
#define HD 64

// (1/sqrt(1024)) * log2(e): folded into Wq conversion; P = exp2(S + bias)
#define QSCALE 0.045084220027780106f
#define MASKBIAS -1e30f

using short8 = __attribute__((ext_vector_type(8))) short;
using short4v = __attribute__((ext_vector_type(4))) short;
using f32x4 = __attribute__((ext_vector_type(4))) float;

__device__ inline short bf16of(float f) {
  union { __hip_bfloat16 b; short s; } u;
  u.b = __float2bfloat16(f);
  return u.s;
}

__device__ inline short4v pack4bf(float a, float b, float c, float d) {
  union { __hip_bfloat162 v[2]; short4v s; } u;
  u.v[0] = __float22bfloat162_rn(make_float2(a, b));
  u.v[1] = __float22bfloat162_rn(make_float2(c, d));
  return u.s;
}

__device__ inline short8 pack8bf(float4 a, float4 b) {
  union { short4v q[2]; short8 o; } u;
  u.q[0] = pack4bf(a.x, a.y, a.z, a.w);
  u.q[1] = pack4bf(b.x, b.y, b.z, b.w);
  return u.o;
}

__device__ inline short8 pack8bf4(f32x4 a, f32x4 b) {
  union { short4v q[2]; short8 o; } u;
  u.q[0] = pack4bf(a[0], a[1], a[2], a[3]);
  u.q[1] = pack4bf(b[0], b[1], b[2], b[3]);
  return u.o;
}

__device__ inline float fexp2(float x) {
#if __has_builtin(__builtin_amdgcn_exp2f)
  return __builtin_amdgcn_exp2f(x);
#else
  return exp2f(x);
#endif
}

#define MFMA(A, B, C) __builtin_amdgcn_mfma_f32_16x16x32_bf16((A), (B), (C), 0, 0, 0)

// ---------------------------------------------------------------------------
// Convert Wo->bf16 (grid-wide), Wq(*QSCALE)/Wk/Wv->bf16 (blocks 0-2),
// mask->bias float (blocks 4-7).
__global__ __launch_bounds__(256) void conv_kernel(
    const float* __restrict__ Wq, const float* __restrict__ Wk,
    const float* __restrict__ Wv, const float* __restrict__ Wo,
    const int* __restrict__ mask, short* __restrict__ Wqb,
    short* __restrict__ Wkb, short* __restrict__ Wvb,
    short* __restrict__ Wob, float* __restrict__ biasf) {
  const int b = blockIdx.x, t = threadIdx.x;
  {
    int i = (b * 256 + t) * 4;  // 1024 blocks cover 1Mi elements of Wo
    float4 v = *(const float4*)&Wo[i];
    *(short4v*)&Wob[i] = pack4bf(v.x, v.y, v.z, v.w);
  }
  if (b < 3) {
    const float* src = (b == 0) ? Wq : (b == 1) ? Wk : Wv;
    short* dst = (b == 0) ? Wqb : (b == 1) ? Wkb : Wvb;
    const float sc = (b == 0) ? QSCALE : 1.0f;
#pragma unroll
    for (int i = 0; i < 4; ++i) {
      int j = t * 16 + i * 4;  // 256*16 = 4096
      float4 v = *(const float4*)&src[j];
      *(short4v*)&dst[j] = pack4bf(v.x * sc, v.y * sc, v.z * sc, v.w * sc);
    }
  } else if (b >= 4 && b < 8) {
    int i = ((b - 4) * 256 + t) * 4;  // 4096 mask ints
    int4 m = *(const int4*)&mask[i];
    float4 o;
    o.x = m.x ? 0.f : MASKBIAS;
    o.y = m.y ? 0.f : MASKBIAS;
    o.z = m.z ? 0.f : MASKBIAS;
    o.w = m.w ? 0.f : MASKBIAS;
    *(float4*)&biasf[i] = o;
  }
}

// ---------------------------------------------------------------------------
// Projections (z=0 Q, z=1 K, z=2 V), bf16 weights pre-converted.
// Block = (ltile 64, nh); LDS-staged x tile, XOR-swizzled.
__global__ __launch_bounds__(256) void proj_mfma(
    const float* __restrict__ xq, const float* __restrict__ xk,
    const float* __restrict__ xv, const short* __restrict__ Wqb,
    const short* __restrict__ Wkb, const short* __restrict__ Wvb,
    short* __restrict__ Qb, short* __restrict__ Kb, short* __restrict__ Vt) {
  __shared__ __align__(16) short xs[64 * 64];
  const int t = threadIdx.x;
  const int wv = t >> 6, lane = t & 63;
  const int quad = lane >> 4, l15 = lane & 15;
  const int z = blockIdx.z, nh = blockIdx.y;
  const int n = nh >> 4, h = nh & 15;
  const int l0 = blockIdx.x * 64;
  const float* x = (z == 0) ? xq : (z == 1) ? xk : xv;
  const short* W = (z == 0) ? Wqb : (z == 1) ? Wkb : Wvb;

  // Stage x tile: 512 16B-chunks; thread handles chunks t, t+256 (coalesced
  // 8 rows x 256 B per instruction), XOR-swizzled.
#pragma unroll
  for (int i = 0; i < 2; ++i) {
    int cc = i * 256 + t, row = cc >> 3, ch = cc & 7;
    const float* g = x + ((size_t)n * LSEQ + l0 + row) * EMB + h * HD + ch * 8;
    float4 a = *(const float4*)g;
    float4 b = *(const float4*)(g + 4);
    *(short8*)&xs[row * 64 + ((ch ^ (row & 7)) * 8)] = pack8bf(a, b);
  }
  __syncthreads();

  f32x4 acc[4];
#pragma unroll
  for (int a = 0; a < 4; ++a) acc[a] = (f32x4){0.f, 0.f, 0.f, 0.f};

  if (z < 2) {
    short8 xf[2];
#pragma unroll
    for (int c = 0; c < 2; ++c)
      xf[c] = *(const short8*)&xs[(wv * 16 + l15) * 64 +
                                  (((c * 4 + quad) ^ (l15 & 7)) * 8)];
#pragma unroll
    for (int c = 0; c < 2; ++c)
#pragma unroll
      for (int mt = 0; mt < 4; ++mt) {
        short8 wf =
            *(const short8*)(W + (mt * 16 + l15) * HD + c * 32 + quad * 8);
        acc[mt] = MFMA(wf, xf[c], acc[mt]);
      }
    short* ob =
        ((z == 0) ? Qb : Kb) + ((size_t)nh * LSEQ + l0 + wv * 16 + l15) * HD;
#pragma unroll
    for (int mt = 0; mt < 4; ++mt)
      *(short4v*)&ob[mt * 16 + quad * 4] =
          pack4bf(acc[mt][0], acc[mt][1], acc[mt][2], acc[mt][3]);
  } else {
    short8 wf[2];
#pragma unroll
    for (int c = 0; c < 2; ++c)
      wf[c] = *(const short8*)(W + (wv * 16 + l15) * HD + c * 32 + quad * 8);
#pragma unroll
    for (int c = 0; c < 2; ++c)
#pragma unroll
      for (int mt = 0; mt < 4; ++mt) {
        short8 af = *(const short8*)&xs[(mt * 16 + l15) * 64 +
                                        (((c * 4 + quad) ^ (l15 & 7)) * 8)];
        acc[mt] = MFMA(af, wf[c], acc[mt]);
      }
    short* vb = Vt + ((size_t)nh * HD + wv * 16 + l15) * LSEQ + l0;
#pragma unroll
    for (int mt = 0; mt < 4; ++mt)
      *(short4v*)&vb[mt * 16 + quad * 4] =
          pack4bf(acc[mt][0], acc[mt][1], acc[mt][2], acc[mt][3]);
  }
}

// ---------------------------------------------------------------------------
// Flash attention, barrier-free. Wave = 64 q, private 16KB LDS (K 8K + V 8K),
// single-buffered, register prefetch. Block = 2 waves; grid (16,32) = 512.
// S^T via MFMA (C-init = mask bias), P stays in registers (pi-permuted V),
// l via ones-MFMA.
__global__ __launch_bounds__(128) void attn_kernel(
    const short* __restrict__ Qg,    // [nh][L][64] bf16 (Wq pre-scaled)
    const short* __restrict__ Kg,    // [nh][L][64] bf16
    const short* __restrict__ Vtg,   // [nh][64][L] bf16
    const float* __restrict__ biasf, // [N][L]: 0 or -1e30
    short* __restrict__ AO)          // [N*L][E] bf16
{
  __shared__ __align__(16) short KV[2][8192];  // per-wave: [0,4096)=K, [4096,8192)=V

  const int t = threadIdx.x;
  const int wv = t >> 6, lane = t & 63;
  const int quad = lane >> 4, l15 = lane & 15;
  const int nh = blockIdx.y;
  const int n = nh >> 4, h = nh & 15;
  const int q0 = blockIdx.x * 128 + wv * 64;

  short* Ksw = &KV[wv][0];
  short* Vsw = &KV[wv][4096];
  const short* kbase = Kg + (size_t)nh * LSEQ * HD;
  const short* vbase = Vtg + (size_t)nh * HD * LSEQ;
  const float* bbase = biasf + n * LSEQ;

  // Resident Q B-fragments: B[d = c*32+quad*8+j][q = ntq*16+l15]
  short8 qf[4][2];
#pragma unroll
  for (int ntq = 0; ntq < 4; ++ntq)
#pragma unroll
    for (int c = 0; c < 2; ++c)
      qf[ntq][c] = *(const short8*)(Qg +
          ((size_t)nh * LSEQ + q0 + ntq * 16 + l15) * HD + c * 32 + quad * 8);

  // Per-wave staging: 64 lanes cover 64 rows x 8 octs; lane -> (srow, sch).
  const int srow = lane >> 3, sch = lane & 7;
  // V pi-placement for oct a=sch: p1 = ((a>>1)&1)*32 + (a&1)*16 + (a>>2)*4
  const int p1 = ((sch >> 1) & 1) * 32 + (sch & 1) * 16 + (sch >> 2) * 4;
  const int ch1 = p1 >> 3, poff = p1 & 7;

  short8 kr[8], vr[8];
#pragma unroll
  for (int i = 0; i < 8; ++i) {
    int row = i * 8 + srow;
    kr[i] = *(const short8*)(kbase + (size_t)row * HD + sch * 8);
    vr[i] = *(const short8*)(vbase + (size_t)row * LSEQ + sch * 8);
  }

  f32x4 O[4][4], Ol[4];
#pragma unroll
  for (int a = 0; a < 4; ++a) {
    Ol[a] = (f32x4){0.f, 0.f, 0.f, 0.f};
#pragma unroll
    for (int b = 0; b < 4; ++b) O[a][b] = (f32x4){0.f, 0.f, 0.f, 0.f};
  }
  const short one_bf = (short)0x3F80;
  const short8 ones = {one_bf, one_bf, one_bf, one_bf,
                       one_bf, one_bf, one_bf, one_bf};

  const int sw0 = ((0 * 4 + quad) ^ (l15 & 7)) * 8;
  const int sw1 = ((1 * 4 + quad) ^ (l15 & 7)) * 8;

  for (int kt = 0; kt < LSEQ / 64; ++kt) {
    // ---- write staged regs -> private LDS (K plain swizzle; V pi-split)
#pragma unroll
    for (int i = 0; i < 8; ++i) {
      int row = i * 8 + srow;
      *(short8*)&Ksw[row * 64 + ((sch ^ (row & 7)) * 8)] = kr[i];
      union { short8 w; short4v h4[2]; } u;
      u.w = vr[i];
      *(short4v*)&Vsw[row * 64 + ((ch1 ^ (row & 7)) * 8) + poff] = u.h4[0];
      *(short4v*)&Vsw[row * 64 + (((ch1 + 1) ^ (row & 7)) * 8) + poff] = u.h4[1];
    }

    const int k0 = kt * 64;
    // ---- S^T = K.Q^T with mask-bias C-init: St[mt(k)][ntq(q)]
    f32x4 St[4][4];
#pragma unroll
    for (int mt = 0; mt < 4; ++mt) {
      f32x4 bv = *(const f32x4*)(bbase + k0 + mt * 16 + quad * 4);
#pragma unroll
      for (int ntq = 0; ntq < 4; ++ntq) St[mt][ntq] = bv;
    }
#pragma unroll
    for (int c = 0; c < 2; ++c) {
      const int sw = c ? sw1 : sw0;
      short8 kf[4];
#pragma unroll
      for (int mt = 0; mt < 4; ++mt)
        kf[mt] = *(const short8*)&Ksw[(mt * 16 + l15) * 64 + sw];
#pragma unroll
      for (int mt = 0; mt < 4; ++mt)
#pragma unroll
        for (int ntq = 0; ntq < 4; ++ntq)
          St[mt][ntq] = MFMA(kf[mt], qf[ntq][c], St[mt][ntq]);
    }

    // ---- P = exp2(St); pack directly into PV A-fragments (pi layout)
#pragma unroll
    for (int mt = 0; mt < 4; ++mt)
#pragma unroll
      for (int ntq = 0; ntq < 4; ++ntq)
#pragma unroll
        for (int r = 0; r < 4; ++r) St[mt][ntq][r] = fexp2(St[mt][ntq][r]);
    short8 pf[4][2];
#pragma unroll
    for (int ntq = 0; ntq < 4; ++ntq)
#pragma unroll
      for (int c = 0; c < 2; ++c)
        pf[ntq][c] = pack8bf4(St[c][ntq], St[c + 2][ntq]);

    // ---- prefetch next tile (regs free for reuse; overlaps PV)
    if (kt < LSEQ / 64 - 1) {
      const int k0n = k0 + 64;
#pragma unroll
      for (int i = 0; i < 8; ++i) {
        int row = i * 8 + srow;
        kr[i] = *(const short8*)(kbase + (size_t)(k0n + row) * HD + sch * 8);
        vr[i] = *(const short8*)(vbase + (size_t)row * LSEQ + k0n + sch * 8);
      }
    }

    // ---- PV + l: O[q][dv] += P.V, Ol += P.1 (A-frags from registers)
#pragma unroll
    for (int c = 0; c < 2; ++c) {
      const int sw = c ? sw1 : sw0;
#pragma unroll
      for (int ntv = 0; ntv < 4; ++ntv) {
        short8 vf = *(const short8*)&Vsw[(ntv * 16 + l15) * 64 + sw];
#pragma unroll
        for (int mq = 0; mq < 4; ++mq) O[mq][ntv] = MFMA(pf[mq][c], vf, O[mq][ntv]);
      }
#pragma unroll
      for (int mq = 0; mq < 4; ++mq) Ol[mq] = MFMA(pf[mq][c], ones, Ol[mq]);
    }
  }

  // ---- epilogue: O/l -> bf16 AO[n*L + q][h*64 + dv]
  short* ob = AO + ((size_t)n * LSEQ + q0) * EMB + h * HD;
#pragma unroll
  for (int mq = 0; mq < 4; ++mq) {
    f32x4 inv;
#pragma unroll
    for (int r = 0; r < 4; ++r) inv[r] = 1.f / Ol[mq][r];
#pragma unroll
    for (int ntv = 0; ntv < 4; ++ntv)
#pragma unroll
      for (int r = 0; r < 4; ++r)
        ob[(size_t)(mq * 16 + quad * 4 + r) * EMB + ntv * 16 + l15] =
            bf16of(O[mq][ntv][r] * inv[r]);
  }
}

// ---------------------------------------------------------------------------
// Out-projection: C[r][j] = sum_e A[r][e]*Wo[j][e] + bo[j].
// 128x64 tile/block, grid (16,32)=512 -> 2 blocks/CU. XOR-swizzled LDS,
// double-buffered, register prefetch. (round-4/5/6 verified)
__global__ __launch_bounds__(256, 2) void outproj_mfma(
    const short* __restrict__ A, const short* __restrict__ W,
    const float* __restrict__ bo, float* __restrict__ C) {
  __shared__ __align__(16) short As[2][128 * 64];
  __shared__ __align__(16) short Bs[2][64 * 64];
  const int t = threadIdx.x;
  const int wq = t >> 6, lane = t & 63;
  const int quad = lane >> 4, l15 = lane & 15;
  const int j0 = blockIdx.x * 64, r0 = blockIdx.y * 128;

  f32x4 acc[2][4];
#pragma unroll
  for (int a = 0; a < 2; ++a)
#pragma unroll
    for (int b = 0; b < 4; ++b) acc[a][b] = (f32x4){0.f, 0.f, 0.f, 0.f};

  short8 ar[4], br[2];
#pragma unroll
  for (int i = 0; i < 4; ++i) {
    int slot = i * 256 + t, row = slot >> 3, ch = slot & 7;
    ar[i] = *(const short8*)(A + (size_t)(r0 + row) * EMB + ch * 8);
  }
#pragma unroll
  for (int i = 0; i < 2; ++i) {
    int slot = i * 256 + t, row = slot >> 3, ch = slot & 7;
    br[i] = *(const short8*)(W + (size_t)(j0 + row) * EMB + ch * 8);
  }
#pragma unroll
  for (int i = 0; i < 4; ++i) {
    int slot = i * 256 + t, row = slot >> 3, ch = slot & 7;
    *(short8*)&As[0][row * 64 + ((ch ^ (row & 7)) * 8)] = ar[i];
  }
#pragma unroll
  for (int i = 0; i < 2; ++i) {
    int slot = i * 256 + t, row = slot >> 3, ch = slot & 7;
    *(short8*)&Bs[0][row * 64 + ((ch ^ (row & 7)) * 8)] = br[i];
  }
  __syncthreads();

  const int sw0 = ((0 * 4 + quad) ^ (l15 & 7)) * 8;
  const int sw1 = ((1 * 4 + quad) ^ (l15 & 7)) * 8;

  for (int ek = 0; ek < EMB; ek += 64) {
    const int cur = (ek >> 6) & 1, nxt = cur ^ 1;
    if (ek + 64 < EMB) {
#pragma unroll
      for (int i = 0; i < 4; ++i) {
        int slot = i * 256 + t, row = slot >> 3, ch = slot & 7;
        ar[i] = *(const short8*)(A + (size_t)(r0 + row) * EMB + ek + 64 + ch * 8);
      }
#pragma unroll
      for (int i = 0; i < 2; ++i) {
        int slot = i * 256 + t, row = slot >> 3, ch = slot & 7;
        br[i] = *(const short8*)(W + (size_t)(j0 + row) * EMB + ek + 64 + ch * 8);
      }
    }
#pragma unroll
    for (int c = 0; c < 2; ++c) {
      const int sw = c ? sw1 : sw0;
      short8 af[2], bf[4];
#pragma unroll
      for (int mt = 0; mt < 2; ++mt)
        af[mt] = *(const short8*)&As[cur][(wq * 32 + mt * 16 + l15) * 64 + sw];
#pragma unroll
      for (int nt = 0; nt < 4; ++nt)
        bf[nt] = *(const short8*)&Bs[cur][(nt * 16 + l15) * 64 + sw];
#pragma unroll
      for (int mt = 0; mt < 2; ++mt)
#pragma unroll
        for (int nt = 0; nt < 4; ++nt)
          acc[mt][nt] = MFMA(af[mt], bf[nt], acc[mt][nt]);
    }
    if (ek + 64 < EMB) {
#pragma unroll
      for (int i = 0; i < 4; ++i) {
        int slot = i * 256 + t, row = slot >> 3, ch = slot & 7;
        *(short8*)&As[nxt][row * 64 + ((ch ^ (row & 7)) * 8)] = ar[i];
      }
#pragma unroll
      for (int i = 0; i < 2; ++i) {
        int slot = i * 256 + t, row = slot >> 3, ch = slot & 7;
        *(short8*)&Bs[nxt][row * 64 + ((ch ^ (row & 7)) * 8)] = br[i];
      }
    }
    __syncthreads();
  }

  float bn[4];
#pragma unroll
  for (int nt = 0; nt < 4; ++nt) bn[nt] = bo[j0 + nt * 16 + l15];
#pragma unroll
  for (int mt = 0; mt < 2; ++mt)
#pragma unroll
    for (int nt = 0; nt < 4; ++nt)
#pragma unroll
      for (int r = 0; r < 4; ++r)
        C[(size_t)(r0 + wq * 32 + mt * 16 + quad * 4 + r) * EMB + j0 +
          nt * 16 + l15] = acc[mt][nt][r] + bn[nt];
}

// ---------------------------------------------------------------------------
extern "C" void kernel_launch(void* const* d_in, const int* in_sizes, int n_in,
                              void* d_out, int out_size, void* d_ws,
                              size_t ws_size, hipStream_t stream) {
  const float* values = (const float*)d_in[0];
  const float* keys   = (const float*)d_in[1];
  const float* query  = (const float*)d_in[2];
  const int*   mask   = (const int*)d_in[3];
  const float* Wv     = (const float*)d_in[4];
  const float* Wk     = (const float*)d_in[5];
  const float* Wq     = (const float*)d_in[6];
  const float* Wo     = (const float*)d_in[7];
  const float* bo     = (const float*)d_in[8];
  float* out = (float*)d_out;

  short* ws = (short*)d_ws;
  const size_t tsz = (size_t)NB * NHEADS * LSEQ * HD;  // 4 Mi shorts
  short* Qb  = ws;
  short* Kb  = Qb + tsz;
  short* Vt  = Kb + tsz;
  short* AOb = Vt + tsz;
  short* Wob = AOb + tsz;                            // 1 Mi shorts
  float* biasf = (float*)(Wob + (size_t)EMB * EMB);  // 4096 floats
  short* Wqb = (short*)(biasf + NB * LSEQ);
  short* Wkb = Wqb + HD * HD;
  short* Wvb = Wkb + HD * HD;

  conv_kernel<<<dim3(1024), dim3(256), 0, stream>>>(Wq, Wk, Wv, Wo, mask, Wqb,
                                                    Wkb, Wvb, Wob, biasf);
  proj_mfma<<<dim3(LSEQ / 64, NB * NHEADS, 3), dim3(256), 0, stream>>>(
      query, keys, values, Wqb, Wkb, Wvb, Qb, Kb, Vt);
  attn_kernel<<<dim3(LSEQ / 128, NB * NHEADS), dim3(128), 0, stream>>>(
      Qb, Kb, Vt, biasf, AOb);
  outproj_mfma<<<dim3(EMB / 64, NB * LSEQ / 128), dim3(256), 0, stream>>>(
      AOb, Wob, bo, out);
}